// Round 5
// baseline (706.763 us; speedup 1.0000x reference)
//
#include <hip/hip_runtime.h>
#include <hip/hip_bf16.h>

// Problem constants
#define B_   128
#define J_   2048
#define N_   32
#define D_   16
#define NJC  32       // j-chunks (64 j each); one s-partial per chunk

// Workspace layout (float offsets):
//  xT     [0, 2097152)            xT[((j*128)+b)*8 + p]        8 MB fp32
//  blogT  [2097152, 6291456)      blogT[(n*J+j)*128 + b]      16 MB bf16
//  mdT    [6291456, 6815744)      mdT[j*128 + b] float2        2 MB
//  s_part [6815744, 8912896)      [jc][b*512+n*16+d]           8 MB fp32
// total 35.7 MB

// ---------------------------------------------------------------------------
// T: xT[(j*128+b)*8+p] = x[b][j][p]   (LDS tile transpose, 256 blocks)
//    Block = 32 j x 32 b tile. Both phases fully coalesced on global side.
// ---------------------------------------------------------------------------
__global__ __launch_bounds__(256) void capsT(const float* __restrict__ x,
                                             float* __restrict__ xT) {
    __shared__ float tile[32 * 260 + 4];          // [32 b][256 f] pad 260
    const int t  = threadIdx.x;
    const int jt = blockIdx.x & 63;               // 64 j-tiles
    const int bt = blockIdx.x >> 6;               // 4 b-tiles
    const int j0 = jt * 32, b0 = bt * 32;

    for (int idx = t; idx < 2048; idx += 256) {   // 2048 float4 = 32KB
        int bl = idx >> 6, f4 = idx & 63;
        float4 v = *(const float4*)(x + (size_t)(b0 + bl) * 16384 + j0 * 8 + f4 * 4);
        *(float4*)&tile[bl * 260 + f4 * 4] = v;
    }
    __syncthreads();
    for (int idx = t; idx < 2048; idx += 256) {
        int jj = idx >> 6, f4o = idx & 63;
        int bl = f4o >> 1, po = (f4o & 1) * 4;
        float4 v = *(const float4*)&tile[bl * 260 + jj * 8 + po];
        *(float4*)(xT + ((size_t)(j0 + jj) * 128 + b0 + bl) * 8 + po) = v;
    }
}

// ---------------------------------------------------------------------------
// A: s_part[jc][b,n,d] = sum_{j in chunk,p} W[n,j,d,p] * (c[b,n,j]*x[b,j,p])
//    Block = (n, jc of 64 j), 256 thr = 4 waves x 16 j. Lane owns b=lane,lane+64.
//    W chunk (32 KB) staged in LDS once, read via uniform-address broadcast
//    ds_read_b128. x via 2x float4 coalesced. 128-VGPR budget for load batching.
// ---------------------------------------------------------------------------
__global__ __launch_bounds__(256, 4) void capsA(const float* __restrict__ W,
                                                const float* __restrict__ xT,
                                                const __hip_bfloat16* __restrict__ blogT,
                                                const float2* __restrict__ mdT,
                                                float* __restrict__ s_part,
                                                int mode) {
    __shared__ float w_lds[64 * 128];  // 32 KB: [jl][d*8+p]
    __shared__ float s_lds[D_ * B_];   // 8 KB:  [d][b]
    const int t    = threadIdx.x;
    const int lane = t & 63;
    const int i    = blockIdx.x;                         // 0..1023
    const int jc   = (i & 7) + 8 * (i >> 8);             // 0..31 (XCD-grouped)
    const int n    = (i >> 3) & 31;
    const int wv   = __builtin_amdgcn_readfirstlane(t >> 6);   // 0..3

    // ---- stage W chunk: 64 j * 512 B, fully coalesced ----
    {
        const float4* wsrc = (const float4*)(W + ((size_t)n * J_ + jc * 64) * 128);
        float4* wdst = (float4*)w_lds;
        #pragma unroll
        for (int q = 0; q < 8; ++q)
            wdst[t + q * 256] = wsrc[t + q * 256];
    }
    __syncthreads();

    float acc[D_][2];
    #pragma unroll
    for (int d = 0; d < D_; ++d) { acc[d][0] = 0.f; acc[d][1] = 0.f; }

    #pragma unroll 2
    for (int jj = 0; jj < 16; ++jj) {
        const int jl = wv * 16 + jj;                     // wave-uniform LDS row
        const int j  = jc * 64 + jl;

        float c0 = 1.0f / 32.0f, c1 = 1.0f / 32.0f;
        if (mode) {
            float lg0 = __bfloat162float(blogT[((size_t)n * J_ + j) * B_ + lane]);
            float lg1 = __bfloat162float(blogT[((size_t)n * J_ + j) * B_ + lane + 64]);
            float2 m0 = mdT[(size_t)j * B_ + lane];
            float2 m1 = mdT[(size_t)j * B_ + lane + 64];
            c0 = __expf(lg0 - m0.x) * m0.y;
            c1 = __expf(lg1 - m1.x) * m1.y;
        }

        const float4* xp0 = (const float4*)(xT + ((size_t)j * 128 + lane) * 8);
        const float4* xp1 = (const float4*)(xT + ((size_t)j * 128 + lane + 64) * 8);
        float4 xa = xp0[0], xb = xp0[1];
        float4 xe = xp1[0], xf = xp1[1];

        float x0[8], x1[8];
        x0[0]=xa.x*c0; x0[1]=xa.y*c0; x0[2]=xa.z*c0; x0[3]=xa.w*c0;
        x0[4]=xb.x*c0; x0[5]=xb.y*c0; x0[6]=xb.z*c0; x0[7]=xb.w*c0;
        x1[0]=xe.x*c1; x1[1]=xe.y*c1; x1[2]=xe.z*c1; x1[3]=xe.w*c1;
        x1[4]=xf.x*c1; x1[5]=xf.y*c1; x1[6]=xf.z*c1; x1[7]=xf.w*c1;

        const float4* wrow = (const float4*)(w_lds + jl * 128);
        #pragma unroll
        for (int d = 0; d < D_; ++d) {
            float4 wa = wrow[d * 2];       // uniform addr -> broadcast, no conflict
            float4 wb = wrow[d * 2 + 1];
            acc[d][0] = fmaf(wa.x, x0[0], acc[d][0]);
            acc[d][1] = fmaf(wa.x, x1[0], acc[d][1]);
            acc[d][0] = fmaf(wa.y, x0[1], acc[d][0]);
            acc[d][1] = fmaf(wa.y, x1[1], acc[d][1]);
            acc[d][0] = fmaf(wa.z, x0[2], acc[d][0]);
            acc[d][1] = fmaf(wa.z, x1[2], acc[d][1]);
            acc[d][0] = fmaf(wa.w, x0[3], acc[d][0]);
            acc[d][1] = fmaf(wa.w, x1[3], acc[d][1]);
            acc[d][0] = fmaf(wb.x, x0[4], acc[d][0]);
            acc[d][1] = fmaf(wb.x, x1[4], acc[d][1]);
            acc[d][0] = fmaf(wb.y, x0[5], acc[d][0]);
            acc[d][1] = fmaf(wb.y, x1[5], acc[d][1]);
            acc[d][0] = fmaf(wb.z, x0[6], acc[d][0]);
            acc[d][1] = fmaf(wb.z, x1[6], acc[d][1]);
            acc[d][0] = fmaf(wb.w, x0[7], acc[d][0]);
            acc[d][1] = fmaf(wb.w, x1[7], acc[d][1]);
        }
    }

    // ---- block-level combine: LDS atomics then one coalesced partial write ----
    for (int q = t; q < D_ * B_; q += 256) s_lds[q] = 0.0f;
    __syncthreads();
    #pragma unroll
    for (int d = 0; d < D_; ++d) {
        atomicAdd(&s_lds[d * B_ + lane],      acc[d][0]);
        atomicAdd(&s_lds[d * B_ + lane + 64], acc[d][1]);
    }
    __syncthreads();
    float* sdst = s_part + (size_t)jc * (B_ * N_ * D_);
    for (int q = t; q < D_ * B_; q += 256) {
        int b = q >> 4, d = q & 15;
        sdst[(size_t)b * (N_ * D_) + n * D_ + d] = s_lds[d * B_ + b];
    }
}

// ---------------------------------------------------------------------------
// R: out[b,n,d] = squash(sum_jc s_part + bias)  (coalesced partial reads)
// ---------------------------------------------------------------------------
__global__ __launch_bounds__(256) void capsR(const float* __restrict__ s_part,
                                             const float* __restrict__ bias,
                                             float* __restrict__ out) {
    int gid = blockIdx.x * 256 + threadIdx.x;       // 65536: b*512 + n*16 + d
    float sv = bias[gid & 511];
    #pragma unroll
    for (int jc = 0; jc < NJC; ++jc)
        sv += s_part[(size_t)jc * 65536 + gid];
    float sq = sv * sv;
    sq += __shfl_xor(sq, 1);
    sq += __shfl_xor(sq, 2);
    sq += __shfl_xor(sq, 4);
    sq += __shfl_xor(sq, 8);
    float scale = sq / (1.0f + sq) / sqrtf(sq + 1e-7f);
    out[gid] = scale * sv;
}

// ---------------------------------------------------------------------------
// B: blogT[n,j,b] (+)= sum_p x[b,j,p] * (sum_d o[b,n,d]*W[n,j,d,p])
//    Same geometry as capsA: LDS-staged W, 256 thr, 16 j per wave.
// ---------------------------------------------------------------------------
__global__ __launch_bounds__(256, 4) void capsB(const float* __restrict__ W,
                                                const float* __restrict__ xT,
                                                const float* __restrict__ o,
                                                __hip_bfloat16* __restrict__ blogT,
                                                int accumulate) {
    __shared__ float w_lds[64 * 128];  // 32 KB
    const int t    = threadIdx.x;
    const int lane = t & 63;
    const int i    = blockIdx.x;
    const int jc   = (i & 7) + 8 * (i >> 8);
    const int n    = (i >> 3) & 31;
    const int wv   = __builtin_amdgcn_readfirstlane(t >> 6);

    {
        const float4* wsrc = (const float4*)(W + ((size_t)n * J_ + jc * 64) * 128);
        float4* wdst = (float4*)w_lds;
        #pragma unroll
        for (int q = 0; q < 8; ++q)
            wdst[t + q * 256] = wsrc[t + q * 256];
    }

    float o0[16], o1[16];
    {
        const float4* p0 = (const float4*)(o + ((size_t)lane * N_ + n) * 16);
        const float4* p1 = (const float4*)(o + ((size_t)(lane + 64) * N_ + n) * 16);
        #pragma unroll
        for (int q = 0; q < 4; ++q) {
            float4 a = p0[q];
            o0[q*4] = a.x; o0[q*4+1] = a.y; o0[q*4+2] = a.z; o0[q*4+3] = a.w;
            float4 b = p1[q];
            o1[q*4] = b.x; o1[q*4+1] = b.y; o1[q*4+2] = b.z; o1[q*4+3] = b.w;
        }
    }
    __syncthreads();

    #pragma unroll 2
    for (int jj = 0; jj < 16; ++jj) {
        const int jl = wv * 16 + jj;
        const int j  = jc * 64 + jl;
        float g0[8] = {0,0,0,0,0,0,0,0};
        float g1[8] = {0,0,0,0,0,0,0,0};
        const float4* wrow = (const float4*)(w_lds + jl * 128);
        #pragma unroll
        for (int d = 0; d < D_; ++d) {
            float4 wa = wrow[d * 2];
            float4 wb = wrow[d * 2 + 1];
            g0[0] = fmaf(wa.x, o0[d], g0[0]); g1[0] = fmaf(wa.x, o1[d], g1[0]);
            g0[1] = fmaf(wa.y, o0[d], g0[1]); g1[1] = fmaf(wa.y, o1[d], g1[1]);
            g0[2] = fmaf(wa.z, o0[d], g0[2]); g1[2] = fmaf(wa.z, o1[d], g1[2]);
            g0[3] = fmaf(wa.w, o0[d], g0[3]); g1[3] = fmaf(wa.w, o1[d], g1[3]);
            g0[4] = fmaf(wb.x, o0[d], g0[4]); g1[4] = fmaf(wb.x, o1[d], g1[4]);
            g0[5] = fmaf(wb.y, o0[d], g0[5]); g1[5] = fmaf(wb.y, o1[d], g1[5]);
            g0[6] = fmaf(wb.z, o0[d], g0[6]); g1[6] = fmaf(wb.z, o1[d], g1[6]);
            g0[7] = fmaf(wb.w, o0[d], g0[7]); g1[7] = fmaf(wb.w, o1[d], g1[7]);
        }
        const float4* xp0 = (const float4*)(xT + ((size_t)j * 128 + lane) * 8);
        const float4* xp1 = (const float4*)(xT + ((size_t)j * 128 + lane + 64) * 8);
        float4 xa = xp0[0], xb = xp0[1];
        float4 xe = xp1[0], xf = xp1[1];
        float t0 = 0.f, t1 = 0.f;
        t0 = fmaf(g0[0], xa.x, t0); t0 = fmaf(g0[1], xa.y, t0);
        t0 = fmaf(g0[2], xa.z, t0); t0 = fmaf(g0[3], xa.w, t0);
        t0 = fmaf(g0[4], xb.x, t0); t0 = fmaf(g0[5], xb.y, t0);
        t0 = fmaf(g0[6], xb.z, t0); t0 = fmaf(g0[7], xb.w, t0);
        t1 = fmaf(g1[0], xe.x, t1); t1 = fmaf(g1[1], xe.y, t1);
        t1 = fmaf(g1[2], xe.z, t1); t1 = fmaf(g1[3], xe.w, t1);
        t1 = fmaf(g1[4], xf.x, t1); t1 = fmaf(g1[5], xf.y, t1);
        t1 = fmaf(g1[6], xf.z, t1); t1 = fmaf(g1[7], xf.w, t1);

        size_t a0 = ((size_t)n * J_ + j) * B_ + lane;
        if (accumulate) {
            t0 += __bfloat162float(blogT[a0]);
            t1 += __bfloat162float(blogT[a0 + 64]);
        }
        blogT[a0]      = __float2bfloat16(t0);
        blogT[a0 + 64] = __float2bfloat16(t1);
    }
}

// ---------------------------------------------------------------------------
// D: per (j,b): m = max_n blogT, inv = 1/sum_n exp(blogT-m)
// ---------------------------------------------------------------------------
__global__ __launch_bounds__(256) void capsD(const __hip_bfloat16* __restrict__ blogT,
                                             float2* __restrict__ mdT) {
    int gid = blockIdx.x * 256 + threadIdx.x;   // 262144 = J_*B_
    float v[32];
    float m = -1e30f;
    #pragma unroll
    for (int nn = 0; nn < 32; ++nn) {
        v[nn] = __bfloat162float(blogT[(size_t)nn * (J_ * B_) + gid]);
        m = fmaxf(m, v[nn]);
    }
    float sum = 0.0f;
    #pragma unroll
    for (int nn = 0; nn < 32; ++nn) sum += __expf(v[nn] - m);
    mdT[gid] = make_float2(m, 1.0f / sum);
}

// ---------------------------------------------------------------------------
extern "C" void kernel_launch(void* const* d_in, const int* in_sizes, int n_in,
                              void* d_out, int out_size, void* d_ws, size_t ws_size,
                              hipStream_t stream) {
    const float* x    = (const float*)d_in[0];   // [128,2048,8]
    const float* W    = (const float*)d_in[1];   // [32,2048,16,8]
    const float* bias = (const float*)d_in[2];   // [32,16]
    float* out = (float*)d_out;                  // [128,32,16]

    float* ws = (float*)d_ws;
    float*           xT     = ws;                                   // 8 MB
    __hip_bfloat16*  blogT  = (__hip_bfloat16*)(ws + 2097152);      // 16 MB bf16
    float2*          mdT    = (float2*)(ws + 2097152 + 4194304);    // 2 MB
    float*           s_part = ws + 2097152 + 4194304 + 524288;      // 8 MB

    dim3 b256(256);

    capsT<<<dim3(256), b256, 0, stream>>>(x, xT);

    // ---- routing iteration 0 (c uniform) ----
    capsA<<<dim3(1024), b256, 0, stream>>>(W, xT, blogT, mdT, s_part, 0);
    capsR<<<dim3(256), b256, 0, stream>>>(s_part, bias, out);
    capsB<<<dim3(1024), b256, 0, stream>>>(W, xT, out, blogT, 0);

    // ---- routing iteration 1 ----
    capsD<<<dim3(1024), b256, 0, stream>>>(blogT, mdT);
    capsA<<<dim3(1024), b256, 0, stream>>>(W, xT, blogT, mdT, s_part, 1);
    capsR<<<dim3(256), b256, 0, stream>>>(s_part, bias, out);
    capsB<<<dim3(1024), b256, 0, stream>>>(W, xT, out, blogT, 1);

    // ---- routing iteration 2 (final) ----
    capsD<<<dim3(1024), b256, 0, stream>>>(blogT, mdT);
    capsA<<<dim3(1024), b256, 0, stream>>>(W, xT, blogT, mdT, s_part, 1);
    capsR<<<dim3(256), b256, 0, stream>>>(s_part, bias, out);
}

// Round 6
// 173.710 us; speedup vs baseline: 4.0686x; 4.0686x over previous
//
#include <hip/hip_runtime.h>
#include <hip/hip_bf16.h>

// Problem constants
#define B_   128
#define J_   2048
#define N_   32
#define D_   16
#define NJC  32       // j-chunks (64 j each); one s-partial per chunk

typedef __attribute__((ext_vector_type(8))) short short8b;  // 8 bf16 (4 VGPRs)
typedef __attribute__((ext_vector_type(4))) float f32x4;    // MFMA acc

__device__ inline short bf16s(float f) {
    union { __hip_bfloat16 h; short s; } u;
    u.h = __float2bfloat16(f);
    return u.s;
}

// Workspace layout (float offsets):
//  xT     [0, 2097152)            xT[(j*128+b)*8 + p]          8 MB fp32
//  blogT  [2097152, 6291456)      blogT[(n*J+j)*128 + b]      16 MB bf16
//  mdT    [6291456, 6815744)      mdT[j*128 + b] float2        2 MB
//  s_part [6815744, 8912896)      [jc][b*512+n*16+d]           8 MB fp32
// total 34 MB

// ---------------------------------------------------------------------------
// T: xT[(j*128+b)*8+p] = x[b][j][p]   (LDS tile transpose)
// ---------------------------------------------------------------------------
__global__ __launch_bounds__(256) void capsT(const float* __restrict__ x,
                                             float* __restrict__ xT) {
    __shared__ float tile[32 * 260 + 4];
    const int t  = threadIdx.x;
    const int jt = blockIdx.x & 63;
    const int bt = blockIdx.x >> 6;
    const int j0 = jt * 32, b0 = bt * 32;

    for (int idx = t; idx < 2048; idx += 256) {
        int bl = idx >> 6, f4 = idx & 63;
        float4 v = *(const float4*)(x + (size_t)(b0 + bl) * 16384 + j0 * 8 + f4 * 4);
        *(float4*)&tile[bl * 260 + f4 * 4] = v;
    }
    __syncthreads();
    for (int idx = t; idx < 2048; idx += 256) {
        int jj = idx >> 6, f4o = idx & 63;
        int bl = f4o >> 1, po = (f4o & 1) * 4;
        float4 v = *(const float4*)&tile[bl * 260 + jj * 8 + po];
        *(float4*)(xT + ((size_t)(j0 + jj) * 128 + b0 + bl) * 8 + po) = v;
    }
}

// ---------------------------------------------------------------------------
// A (MFMA): per (n, jc): s_part[jc][b, n, d] = y(b,K) x W(K,d), K = 64j*8p = 512
//   y[b,(j,p)] = c[b,n,j] * x[b,j,p]  built in registers as bf16 A-fragments.
//   256 thr = 4 waves; wave wv owns b-tiles [wv*32, wv*32+16) and [+16, +32).
//   mfma_f32_16x16x32_bf16: A row = lane&15, k = (lane>>4)*8+i (j=lane>>4, p=i);
//   B col(d) = lane&15, same k; D row = (lane>>4)*4+r, col = lane&15 (m89 layout).
//   Acc lives in MFMA accumulator regs -> no persistent-VGPR-array pathology.
// ---------------------------------------------------------------------------
__global__ __launch_bounds__(256) void capsA(const float* __restrict__ W,
                                             const float* __restrict__ xT,
                                             const __hip_bfloat16* __restrict__ blogT,
                                             const float2* __restrict__ mdT,
                                             float* __restrict__ s_part,
                                             int mode) {
    const int t     = threadIdx.x;
    const int lane  = t & 63;
    const int i     = blockIdx.x;                    // 0..1023
    const int jc    = (i & 7) + 8 * (i >> 8);        // 0..31 (XCD-grouped)
    const int n     = (i >> 3) & 31;
    const int wv    = t >> 6;                        // 0..3
    const int colid = lane & 15;                     // d for B / b_low for A
    const int kgrp  = lane >> 4;                     // 0..3 -> j within K-step

    const int b0 = wv * 32 + colid;                  // A row, tile 0
    const int b1 = b0 + 16;                          // A row, tile 1

    f32x4 acc0 = {0.f, 0.f, 0.f, 0.f};
    f32x4 acc1 = {0.f, 0.f, 0.f, 0.f};

    for (int ks = 0; ks < 16; ++ks) {
        const int j = jc * 64 + ks * 4 + kgrp;       // per-lane j

        // ---- B-fragment: W[n][j][d=colid][0..7] -> bf16x8 (coalesced 512B/quarter-wave)
        const float4* wp = (const float4*)(W + (((size_t)n * J_ + j) * 16 + colid) * 8);
        float4 wa = wp[0], wb = wp[1];
        short8b bfrag;
        bfrag[0] = bf16s(wa.x); bfrag[1] = bf16s(wa.y);
        bfrag[2] = bf16s(wa.z); bfrag[3] = bf16s(wa.w);
        bfrag[4] = bf16s(wb.x); bfrag[5] = bf16s(wb.y);
        bfrag[6] = bf16s(wb.z); bfrag[7] = bf16s(wb.w);

        // ---- coupling coefficients for (b0,j) and (b1,j)
        float c0 = 1.0f / 32.0f, c1 = 1.0f / 32.0f;
        if (mode) {
            float lg0 = __bfloat162float(blogT[((size_t)n * J_ + j) * B_ + b0]);
            float lg1 = __bfloat162float(blogT[((size_t)n * J_ + j) * B_ + b1]);
            float2 m0 = mdT[(size_t)j * B_ + b0];
            float2 m1 = mdT[(size_t)j * B_ + b1];
            c0 = __expf(lg0 - m0.x) * m0.y;
            c1 = __expf(lg1 - m1.x) * m1.y;
        }

        // ---- A-fragment tile 0: y[b0][j][0..7]
        const float4* xp0 = (const float4*)(xT + ((size_t)j * 128 + b0) * 8);
        float4 xa = xp0[0], xb = xp0[1];
        short8b afrag0;
        afrag0[0] = bf16s(xa.x * c0); afrag0[1] = bf16s(xa.y * c0);
        afrag0[2] = bf16s(xa.z * c0); afrag0[3] = bf16s(xa.w * c0);
        afrag0[4] = bf16s(xb.x * c0); afrag0[5] = bf16s(xb.y * c0);
        afrag0[6] = bf16s(xb.z * c0); afrag0[7] = bf16s(xb.w * c0);

        // ---- A-fragment tile 1: y[b1][j][0..7]
        const float4* xp1 = (const float4*)(xT + ((size_t)j * 128 + b1) * 8);
        float4 xe = xp1[0], xf = xp1[1];
        short8b afrag1;
        afrag1[0] = bf16s(xe.x * c1); afrag1[1] = bf16s(xe.y * c1);
        afrag1[2] = bf16s(xe.z * c1); afrag1[3] = bf16s(xe.w * c1);
        afrag1[4] = bf16s(xf.x * c1); afrag1[5] = bf16s(xf.y * c1);
        afrag1[6] = bf16s(xf.z * c1); afrag1[7] = bf16s(xf.w * c1);

        acc0 = __builtin_amdgcn_mfma_f32_16x16x32_bf16(afrag0, bfrag, acc0, 0, 0, 0);
        acc1 = __builtin_amdgcn_mfma_f32_16x16x32_bf16(afrag1, bfrag, acc1, 0, 0, 0);
    }

    // ---- store: D row=(lane>>4)*4+r (=b_local), col=lane&15 (=d); disjoint per block
    float* sdst = s_part + (size_t)jc * (B_ * N_ * D_);
    #pragma unroll
    for (int r = 0; r < 4; ++r) {
        int brow = wv * 32 + kgrp * 4 + r;
        sdst[(size_t)brow * 512 + n * 16 + colid]        = acc0[r];
        sdst[(size_t)(brow + 16) * 512 + n * 16 + colid] = acc1[r];
    }
}

// ---------------------------------------------------------------------------
// R: out[b,n,d] = squash(sum_jc s_part + bias)
// ---------------------------------------------------------------------------
__global__ __launch_bounds__(256) void capsR(const float* __restrict__ s_part,
                                             const float* __restrict__ bias,
                                             float* __restrict__ out) {
    int gid = blockIdx.x * 256 + threadIdx.x;       // 65536: b*512 + n*16 + d
    float sv = bias[gid & 511];
    #pragma unroll
    for (int jc = 0; jc < NJC; ++jc)
        sv += s_part[(size_t)jc * 65536 + gid];
    float sq = sv * sv;
    sq += __shfl_xor(sq, 1);
    sq += __shfl_xor(sq, 2);
    sq += __shfl_xor(sq, 4);
    sq += __shfl_xor(sq, 8);
    float scale = sq / (1.0f + sq) / sqrtf(sq + 1e-7f);
    out[gid] = scale * sv;
}

// ---------------------------------------------------------------------------
// B: blogT[n,j,b] (+)= sum_p x[b,j,p] * (sum_d o[b,n,d]*W[n,j,d,p])
//    Round-4 structure (ran at ~VALU peak): 512 thr = 8 waves x 8 j,
//    per-j fresh g accumulators, o read-only in 32 VGPRs, direct W float4.
// ---------------------------------------------------------------------------
__global__ __launch_bounds__(512, 8) void capsB(const float* __restrict__ W,
                                                const float* __restrict__ xT,
                                                const float* __restrict__ o,
                                                __hip_bfloat16* __restrict__ blogT,
                                                int accumulate) {
    const int t    = threadIdx.x;
    const int lane = t & 63;
    const int i    = blockIdx.x;                         // 0..1023
    const int jc   = (i & 7) + 8 * (i >> 8);
    const int n    = (i >> 3) & 31;
    const int wv   = __builtin_amdgcn_readfirstlane(t >> 6);
    const int jbase = jc * 64 + wv * 8;

    float o0[16], o1[16];
    {
        const float4* p0 = (const float4*)(o + ((size_t)lane * N_ + n) * 16);
        const float4* p1 = (const float4*)(o + ((size_t)(lane + 64) * N_ + n) * 16);
        #pragma unroll
        for (int q = 0; q < 4; ++q) {
            float4 a = p0[q];
            o0[q*4] = a.x; o0[q*4+1] = a.y; o0[q*4+2] = a.z; o0[q*4+3] = a.w;
            float4 b = p1[q];
            o1[q*4] = b.x; o1[q*4+1] = b.y; o1[q*4+2] = b.z; o1[q*4+3] = b.w;
        }
    }

    for (int jj = 0; jj < 8; ++jj) {
        const int j = jbase + jj;                        // wave-uniform
        float g0[8] = {0,0,0,0,0,0,0,0};
        float g1[8] = {0,0,0,0,0,0,0,0};
        const float4* wp4 = (const float4*)(W + ((size_t)n * J_ + j) * 128);
        #pragma unroll
        for (int d = 0; d < D_; ++d) {
            float4 wa = wp4[d * 2];
            float4 wb = wp4[d * 2 + 1];
            g0[0] = fmaf(wa.x, o0[d], g0[0]); g1[0] = fmaf(wa.x, o1[d], g1[0]);
            g0[1] = fmaf(wa.y, o0[d], g0[1]); g1[1] = fmaf(wa.y, o1[d], g1[1]);
            g0[2] = fmaf(wa.z, o0[d], g0[2]); g1[2] = fmaf(wa.z, o1[d], g1[2]);
            g0[3] = fmaf(wa.w, o0[d], g0[3]); g1[3] = fmaf(wa.w, o1[d], g1[3]);
            g0[4] = fmaf(wb.x, o0[d], g0[4]); g1[4] = fmaf(wb.x, o1[d], g1[4]);
            g0[5] = fmaf(wb.y, o0[d], g0[5]); g1[5] = fmaf(wb.y, o1[d], g1[5]);
            g0[6] = fmaf(wb.z, o0[d], g0[6]); g1[6] = fmaf(wb.z, o1[d], g1[6]);
            g0[7] = fmaf(wb.w, o0[d], g0[7]); g1[7] = fmaf(wb.w, o1[d], g1[7]);
        }
        const float4* xp0 = (const float4*)(xT + ((size_t)j * 128 + lane) * 8);
        const float4* xp1 = (const float4*)(xT + ((size_t)j * 128 + lane + 64) * 8);
        float4 xa = xp0[0], xb = xp0[1];
        float4 xe = xp1[0], xf = xp1[1];
        float t0 = 0.f, t1 = 0.f;
        t0 = fmaf(g0[0], xa.x, t0); t0 = fmaf(g0[1], xa.y, t0);
        t0 = fmaf(g0[2], xa.z, t0); t0 = fmaf(g0[3], xa.w, t0);
        t0 = fmaf(g0[4], xb.x, t0); t0 = fmaf(g0[5], xb.y, t0);
        t0 = fmaf(g0[6], xb.z, t0); t0 = fmaf(g0[7], xb.w, t0);
        t1 = fmaf(g1[0], xe.x, t1); t1 = fmaf(g1[1], xe.y, t1);
        t1 = fmaf(g1[2], xe.z, t1); t1 = fmaf(g1[3], xe.w, t1);
        t1 = fmaf(g1[4], xf.x, t1); t1 = fmaf(g1[5], xf.y, t1);
        t1 = fmaf(g1[6], xf.z, t1); t1 = fmaf(g1[7], xf.w, t1);

        size_t a0 = ((size_t)n * J_ + j) * B_ + lane;
        if (accumulate) {
            t0 += __bfloat162float(blogT[a0]);
            t1 += __bfloat162float(blogT[a0 + 64]);
        }
        blogT[a0]      = __float2bfloat16(t0);
        blogT[a0 + 64] = __float2bfloat16(t1);
    }
}

// ---------------------------------------------------------------------------
// D: per (j,b): m = max_n blogT, inv = 1/sum_n exp(blogT-m)
// ---------------------------------------------------------------------------
__global__ __launch_bounds__(256) void capsD(const __hip_bfloat16* __restrict__ blogT,
                                             float2* __restrict__ mdT) {
    int gid = blockIdx.x * 256 + threadIdx.x;   // 262144 = J_*B_
    float v[32];
    float m = -1e30f;
    #pragma unroll
    for (int nn = 0; nn < 32; ++nn) {
        v[nn] = __bfloat162float(blogT[(size_t)nn * (J_ * B_) + gid]);
        m = fmaxf(m, v[nn]);
    }
    float sum = 0.0f;
    #pragma unroll
    for (int nn = 0; nn < 32; ++nn) sum += __expf(v[nn] - m);
    mdT[gid] = make_float2(m, 1.0f / sum);
}

// ---------------------------------------------------------------------------
extern "C" void kernel_launch(void* const* d_in, const int* in_sizes, int n_in,
                              void* d_out, int out_size, void* d_ws, size_t ws_size,
                              hipStream_t stream) {
    const float* x    = (const float*)d_in[0];   // [128,2048,8]
    const float* W    = (const float*)d_in[1];   // [32,2048,16,8]
    const float* bias = (const float*)d_in[2];   // [32,16]
    float* out = (float*)d_out;                  // [128,32,16]

    float* ws = (float*)d_ws;
    float*           xT     = ws;                                   // 8 MB
    __hip_bfloat16*  blogT  = (__hip_bfloat16*)(ws + 2097152);      // 16 MB bf16
    float2*          mdT    = (float2*)(ws + 2097152 + 4194304);    // 2 MB
    float*           s_part = ws + 2097152 + 4194304 + 524288;      // 8 MB

    dim3 b256(256), b512(512);

    capsT<<<dim3(256), b256, 0, stream>>>(x, xT);

    // ---- routing iteration 0 (c uniform) ----
    capsA<<<dim3(1024), b256, 0, stream>>>(W, xT, blogT, mdT, s_part, 0);
    capsR<<<dim3(256), b256, 0, stream>>>(s_part, bias, out);
    capsB<<<dim3(1024), b512, 0, stream>>>(W, xT, out, blogT, 0);

    // ---- routing iteration 1 ----
    capsD<<<dim3(1024), b256, 0, stream>>>(blogT, mdT);
    capsA<<<dim3(1024), b256, 0, stream>>>(W, xT, blogT, mdT, s_part, 1);
    capsR<<<dim3(256), b256, 0, stream>>>(s_part, bias, out);
    capsB<<<dim3(1024), b512, 0, stream>>>(W, xT, out, blogT, 1);

    // ---- routing iteration 2 (final) ----
    capsD<<<dim3(1024), b256, 0, stream>>>(blogT, mdT);
    capsA<<<dim3(1024), b256, 0, stream>>>(W, xT, blogT, mdT, s_part, 1);
    capsR<<<dim3(256), b256, 0, stream>>>(s_part, bias, out);
}